// Round 10
// baseline (36.785 us; speedup 1.0000x reference)
//
#include <hip/hip_runtime.h>

// KernelExpansion: out[m] = sum_n sigma^2 * w[n] * exp(-0.5*||s_n - x_m||^2 / l^2)
// Round-10: single fused kernel; s-chunk staged in LDS in fragment order.
//  - prep kernel DELETED: each block re-preps its own 256 s-rows (one per
//    thread, ~50 VALU ops) straight into LDS; x-frags staged through the same
//    32KB LDS in phase 1, then the buffer is reused for s.
//  - LDS layout = MFMA fragment order: slot = tile*64 + lane, 16B per slot
//    -> main-loop ds_read_b128 is linear (2 lanes/bank = conflict-free).
//  - K-pad constant folding kept (r8): acc IS the exp2 argument:
//    A[n,24..25]=lw hi/lo (lw=log2(sg^2 w_n)+c2||s||^2), A[n,26..27]=1 (x side: 1,1,cx_hi,cx_lo)
//  - occupancy: 32KB LDS -> 5 blocks/CU; launch_bounds(256,5) (VGPR cap 102).
// C/D layout (verified r4 pass): acc[i] -> n-row q*4+i, m-col r.

#define LOG2E_F 1.4426950408889634f

typedef __attribute__((ext_vector_type(8))) short bf16x8;   // 8 bf16 = 4 VGPRs
typedef __attribute__((ext_vector_type(4))) float f32x4;
typedef float v2f_ __attribute__((ext_vector_type(2)));

constexpr int D      = 24;
constexpr int TILES  = 4;    // 16-col tiles per wave -> 64 m per wave
constexpr int NSPLIT = 32;   // n-chunks of 256 rows; blocks = (M/256)*NSPLIT
constexpr int CT     = 16;   // tiles per chunk (256 rows)
constexpr int TPB    = 256;

__device__ inline unsigned short f32_to_bf16_rne(float f) {
    unsigned u = __builtin_bit_cast(unsigned, f);
    u += 0x7fffu + ((u >> 16) & 1u);
    return (unsigned short)(u >> 16);
}
__device__ inline float bf16_to_f32(unsigned short h) {
    unsigned u = ((unsigned)h) << 16;
    return __builtin_bit_cast(float, u);
}

constexpr unsigned short BF16_ONE = 0x3F80;

__device__ inline float load_row24(const float* __restrict__ src, float* v) {
    float ssq = 0.f;
#pragma unroll
    for (int i = 0; i < 6; ++i) {
        float4 f = reinterpret_cast<const float4*>(src)[i];
        v[4*i+0] = f.x; v[4*i+1] = f.y; v[4*i+2] = f.z; v[4*i+3] = f.w;
    }
#pragma unroll
    for (int d = 0; d < 24; ++d) ssq = fmaf(v[d], v[d], ssq);
    return ssq;
}

// Write one row (32 cols, hi+lo) into LDS in fragment order.
// split_at_26: true -> cols {24,25}=1, {26,27}=splitval hi/lo  (x rows)
//              false -> cols {24,25}=splitval hi/lo, {26,27}=1 (s rows)
__device__ inline void stage_row(unsigned short* __restrict__ sm, int t,
                                 const float* __restrict__ v, float scale,
                                 float splitval, bool split_at_26) {
    unsigned short hi[32], lo[32];
#pragma unroll
    for (int d = 0; d < 24; ++d) {
        float vs = scale * v[d];
        unsigned short h = f32_to_bf16_rne(vs);
        hi[d] = h;
        lo[d] = f32_to_bf16_rne(vs - bf16_to_f32(h));
    }
    unsigned short shv = f32_to_bf16_rne(splitval);
    unsigned short slv = f32_to_bf16_rne(splitval - bf16_to_f32(shv));
    if (split_at_26) { hi[24] = BF16_ONE; hi[25] = BF16_ONE; hi[26] = shv; hi[27] = slv; }
    else             { hi[24] = shv; hi[25] = slv; hi[26] = BF16_ONE; hi[27] = BF16_ONE; }
    hi[28] = 0; hi[29] = 0; hi[30] = 0; hi[31] = 0;
#pragma unroll
    for (int d = 24; d < 32; ++d) lo[d] = 0;
    int sb = (t >> 4) * 512 + (t & 15) * 8;   // short index of (tile, r) slot base
#pragma unroll
    for (int q2 = 0; q2 < 4; ++q2) {
        bf16x8 vh, vl;
#pragma unroll
        for (int j2 = 0; j2 < 8; ++j2) { vh[j2] = (short)hi[q2*8+j2]; vl[j2] = (short)lo[q2*8+j2]; }
        *reinterpret_cast<bf16x8*>(sm + sb + q2 * 128) = vh;
        *reinterpret_cast<bf16x8*>(sm + 8192 + sb + q2 * 128) = vl;
    }
}

__global__ __launch_bounds__(TPB, 5) void ke_fused(
    const float* __restrict__ x, const float* __restrict__ s,
    const float* __restrict__ wts,
    const float* __restrict__ sigma_p, const float* __restrict__ length_p,
    float* __restrict__ out, int M, int N, int MGRP) {
    __shared__ __align__(16) unsigned short sm[16384];  // 32KB: hi [0,8192) lo [8192,16384)
    int t    = threadIdx.x;
    int lane = t & 63;
    int wv   = t >> 6;
    int mg   = blockIdx.x % MGRP;
    int ns   = blockIdx.x / MGRP;
    int r    = lane & 15;

    float l    = length_p[0];
    float c2   = -0.5f * LOG2E_F / (l * l);
    float m2c2 = -2.f * c2;
    float sg   = sigma_p[0];

    float v[24];
    // ---- phase 1: stage this block's 256 x-rows, pick up B fragments
    {
        int row = mg * 256 + t;
        float ssq = load_row24(x + (size_t)row * D, v);
        stage_row(sm, t, v, 1.f, c2 * ssq, true);
    }
    __syncthreads();
    bf16x8 bh[TILES], bl[TILES];
#pragma unroll
    for (int j = 0; j < TILES; ++j) {
        int si = ((wv * 4 + j) * 64 + lane) * 8;
        bh[j] = *reinterpret_cast<const bf16x8*>(sm + si);
        bl[j] = *reinterpret_cast<const bf16x8*>(sm + 8192 + si);
    }
#pragma unroll
    for (int j = 0; j < TILES; ++j) { asm("" : "+v"(bh[j]), "+v"(bl[j])); }
    __syncthreads();
    // ---- phase 2: stage this block's 256 s-rows (n-chunk) into the same LDS
    {
        int row = ns * 256 + t;
        float ssq = load_row24(s + (size_t)row * D, v);
        float lwt = __log2f(sg * sg * wts[row]) + c2 * ssq;
        lwt = fmaxf(lwt, -20000.f);              // w -> 0: finite, exp2 -> 0
        stage_row(sm, t, v, m2c2, lwt, false);
    }
    __syncthreads();
    // ---- main loop: 16 tiles from LDS (linear, conflict-free)
    float p[TILES] = {0.f, 0.f, 0.f, 0.f};
#pragma unroll 1
    for (int tt = 0; tt < CT; ++tt) {
        bf16x8 ah = *reinterpret_cast<const bf16x8*>(sm + (tt * 64 + lane) * 8);
        bf16x8 al = *reinterpret_cast<const bf16x8*>(sm + 8192 + (tt * 64 + lane) * 8);
#pragma unroll
        for (int j = 0; j < TILES; ++j) {
            f32x4 z = {0.f, 0.f, 0.f, 0.f};
            f32x4 acc = __builtin_amdgcn_mfma_f32_16x16x32_bf16(ah, bh[j], z, 0, 0, 0);
            acc = __builtin_amdgcn_mfma_f32_16x16x32_bf16(al, bh[j], acc, 0, 0, 0);
            acc = __builtin_amdgcn_mfma_f32_16x16x32_bf16(ah, bl[j], acc, 0, 0, 0);
            float e0 = __builtin_amdgcn_exp2f(acc[0]);
            float e1 = __builtin_amdgcn_exp2f(acc[1]);
            float e2 = __builtin_amdgcn_exp2f(acc[2]);
            float e3 = __builtin_amdgcn_exp2f(acc[3]);
            p[j] += (e0 + e1) + (e2 + e3);
        }
    }
    // reduce over the 4 q-quarters (column r fixed) and accumulate
#pragma unroll
    for (int j = 0; j < TILES; ++j) {
        p[j] += __shfl_xor(p[j], 16, 64);
        p[j] += __shfl_xor(p[j], 32, 64);
    }
    if (lane < 16) {
        int m0 = mg * 256 + wv * 64;
#pragma unroll
        for (int j = 0; j < TILES; ++j)
            atomicAdd(&out[m0 + j * 16 + r], p[j]);
    }
}

// ---- fallback: fp32 VALU kernel (no workspace needed)
constexpr int MPT  = 2;
constexpr int MBLK = TPB * MPT;

__global__ __launch_bounds__(TPB) void ke_plain(
    const float* __restrict__ x, const float* __restrict__ samples,
    const float* __restrict__ weights, const float* __restrict__ sigma_p,
    const float* __restrict__ length_p, float* __restrict__ out,
    int M, int N, int nsplit, int chunk) {
    int mb = blockIdx.x / nsplit;
    int ns = blockIdx.x - mb * nsplit;
    int t  = threadIdx.x;
    int m0 = mb * MBLK + t;
    int m1 = m0 + TPB;
    int m0c = (m0 < M) ? m0 : 0;
    int m1c = (m1 < M) ? m1 : 0;

    v2f_ xaq[D / 2], xbq[D / 2];
    const v2f_* xp0 = reinterpret_cast<const v2f_*>(x + (size_t)m0c * D);
    const v2f_* xp1 = reinterpret_cast<const v2f_*>(x + (size_t)m1c * D);
#pragma unroll
    for (int qq = 0; qq < D / 2; ++qq) { xaq[qq] = xp0[qq]; xbq[qq] = xp1[qq]; }
#pragma unroll
    for (int qq = 0; qq < D / 2; ++qq) { asm("" : "+v"(xaq[qq])); asm("" : "+v"(xbq[qq])); }

    float l   = length_p[0];
    float c   = -0.5f * LOG2E_F / (l * l);
    float m2c = -2.f * c;
    float sg  = sigma_p[0];
    float sg2 = sg * sg;

    v2f_ qa = {0.f, 0.f}, qb = {0.f, 0.f};
#pragma unroll
    for (int qq = 0; qq < D / 2; ++qq) {
        qa = __builtin_elementwise_fma(xaq[qq], xaq[qq], qa);
        qb = __builtin_elementwise_fma(xbq[qq], xbq[qq], qb);
    }
    float cxa = c * (qa.x + qa.y);
    float cxb = c * (qb.x + qb.y);

    float acc0 = 0.f, acc1 = 0.f;
    int n0 = ns * chunk;
    int n1 = n0 + chunk;
    if (n1 > N) n1 = N;
#pragma unroll 2
    for (int n = n0; n < n1; ++n) {
        const v2f_* s2 = reinterpret_cast<const v2f_*>(samples + (size_t)n * D);
        v2f_ da = {0.f, 0.f}, db = {0.f, 0.f}, sq = {0.f, 0.f};
#pragma unroll
        for (int qq = 0; qq < D / 2; ++qq) {
            v2f_ sv = s2[qq];
            sq = __builtin_elementwise_fma(sv, sv, sq);
            da = __builtin_elementwise_fma(sv, xaq[qq], da);
            db = __builtin_elementwise_fma(sv, xbq[qq], db);
        }
        float cn = c * (sq.x + sq.y);
        float wn = sg2 * weights[n];
        float e0 = fmaf(m2c, da.x + da.y, cn);
        float e1 = fmaf(m2c, db.x + db.y, cn);
        acc0 = fmaf(wn, __builtin_amdgcn_exp2f(e0), acc0);
        acc1 = fmaf(wn, __builtin_amdgcn_exp2f(e1), acc1);
    }
    if (m0 < M) atomicAdd(&out[m0], acc0 * __builtin_amdgcn_exp2f(cxa));
    if (m1 < M) atomicAdd(&out[m1], acc1 * __builtin_amdgcn_exp2f(cxb));
}

extern "C" void kernel_launch(void* const* d_in, const int* in_sizes, int n_in,
                              void* d_out, int out_size, void* d_ws, size_t ws_size,
                              hipStream_t stream) {
    const float* x       = (const float*)d_in[0];
    const float* samples = (const float*)d_in[1];
    const float* weights = (const float*)d_in[2];
    const float* sigma_p = (const float*)d_in[3];
    const float* length_p= (const float*)d_in[4];
    float* out = (float*)d_out;

    int M = in_sizes[0] / D;
    int N = in_sizes[1] / D;

    hipMemsetAsync(out, 0, (size_t)out_size * sizeof(float), stream);

    bool fused_ok = (M % 256) == 0 && (N == NSPLIT * CT * 16) && out_size >= M;

    if (fused_ok) {
        int MGRP   = M / 256;                 // 64
        int blocks = MGRP * NSPLIT;           // 2048
        ke_fused<<<dim3(blocks), dim3(TPB), 0, stream>>>(
            x, samples, weights, sigma_p, length_p, out, M, N, MGRP);
    } else {
        int mbcnt  = (M + MBLK - 1) / MBLK;
        int nsplit = 2048 / (mbcnt > 0 ? mbcnt : 1);
        if (nsplit < 1) nsplit = 1;
        if (nsplit > N) nsplit = N;
        int chunk = (N + nsplit - 1) / nsplit;
        ke_plain<<<dim3(mbcnt * nsplit), dim3(TPB), 0, stream>>>(
            x, samples, weights, sigma_p, length_p, out, M, N, nsplit, chunk);
    }
}